// Round 2
// baseline (136.884 us; speedup 1.0000x reference)
//
#include <hip/hip_runtime.h>
#include <hip/hip_bf16.h>
#include <stdint.h>

// out = X @ Bbig + bias; X = (32768 x 1024) fp32 (real||imag)
// Bbig assembled from TT factors (verified formula from round 1):
//   n<512:  B[k][n] = Wr[n][k] (k<512), -Wi[n][k-512] (k>=512)
//   n>=512: B[k][n] = Wi[n-512][k] (k<512), Wr[n-512][k-512] (k>=512)
// GEMM: M=32768, K=1024, N=1024, fp16 MFMA 16x16x32, fp32 accum.
// Structure: 256x256 tile, BK=64, 8 waves (2Mx4N), 4-phase/K-tile pipelined
// schedule (8-phase-template style): raw barriers + counted vmcnt + setprio.
// B global image is pre-swizzled so linear global_load_lds yields the
// swizzled LDS layout; A is reg-staged with fp32->fp16 cvt + swizzled ds_write.

typedef _Float16 half8 __attribute__((ext_vector_type(8)));
typedef _Float16 half4v __attribute__((ext_vector_type(4)));
typedef float f32x4 __attribute__((ext_vector_type(4)));

typedef __attribute__((address_space(3))) void* lds_ptr_t;
typedef const __attribute__((address_space(1))) void* gbl_ptr_t;

__device__ __forceinline__ void gload_lds16(const void* g, void* s) {
  // lane l's 16B from g (per-lane addr) land at (wave-uniform) s + l*16
  __builtin_amdgcn_global_load_lds((gbl_ptr_t)g, (lds_ptr_t)s, 16, 0, 0);
}

#define BAR() __builtin_amdgcn_s_barrier()
#define PRIO1() __builtin_amdgcn_s_setprio(1)
#define PRIO0() __builtin_amdgcn_s_setprio(0)

// ---------------- Kernel 1: build swizzled B image ----------------
// BTimg[nt][kt][row 0..255][kcol 0..63], byte addr within 32KB tile:
//   row*128 + ((kcol*2) ^ ((row&7)<<4))
__global__ void build_bt(const float* __restrict__ G1R, const float* __restrict__ G2R,
                         const float* __restrict__ G1I, const float* __restrict__ G2I,
                         _Float16* __restrict__ BTimg) {
  int idx = blockIdx.x * 256 + threadIdx.x;  // 0 .. 1M-1
  int kcol = idx & 63;
  int row  = (idx >> 6) & 255;
  int kt   = (idx >> 14) & 15;
  int nt   = idx >> 18;
  int n = nt * 256 + row;
  int k = kt * 64 + kcol;
  int o = n & 511, i = k & 511;
  bool imagOut = n >= 512, kHi = k >= 512;
  const float* G1; const float* G2; float sign = 1.0f;
  if (imagOut == kHi) { G1 = G1R; G2 = G2R; }
  else { G1 = G1I; G2 = G2I; if (!imagOut) sign = -1.0f; }
  int b = o >> 4, e = o & 15, d = i >> 4, g = i & 15;
  float w = 0.0f;
#pragma unroll
  for (int c = 0; c < 4; ++c)
    w += G1[b * 128 + c * 32 + d] * G2[c * 256 + e * 16 + g];
  size_t byteoff = ((size_t)(nt * 16 + kt) << 15) + (size_t)row * 128
                 + ((kcol * 2) ^ ((row & 7) << 4));
  *(_Float16*)((char*)BTimg + byteoff) = (_Float16)(sign * w);
}

// ---------------- Kernel 2: GEMM ----------------
__global__ __launch_bounds__(512, 2) void tt_gemm(
    const float* __restrict__ A,       // 32768 x 1024 fp32
    const _Float16* __restrict__ Bimg, // swizzled tile images, 2 MB
    const float* __restrict__ bias_r, const float* __restrict__ bias_i,
    float* __restrict__ C) {           // 32768 x 1024 fp32
  __shared__ __align__(16) _Float16 Als[2][16384];  // [buf][256 rows][64 k] swz
  __shared__ __align__(16) _Float16 Bls[2][16384];

  const int tid = threadIdx.x;
  const int bid = blockIdx.x;
  // XCD swizzle: 512 blocks, 64/XCD contiguous; nt fastest -> A-panel L2 reuse
  const int bid2 = (bid & 7) * 64 + (bid >> 3);
  const int mt = bid2 >> 2, nt = bid2 & 3;
  const int row0 = mt * 256, col0 = nt * 256;

  const int lane = tid & 63, wid = tid >> 6;
  const int wm = wid >> 2, wn = wid & 3;   // wave -> 128x64 C subtile
  const int lr = lane & 15, lq = lane >> 4;

  const int arow = tid >> 4;               // 0..31
  const int acol = (tid & 15) * 4;         // float col within BK=64
  const float* Abase = A + (size_t)row0 * 1024;

  f32x4 acc[8][4] = {};
  float4 areg[8];
  half8 afr[4][2], bfr0[2][2], bfr1[2][2];

  auto aissue = [&](int t, int i0) {
#pragma unroll
    for (int i = 0; i < 4; ++i) {
      int ii = i0 + i;
      areg[ii] = *(const float4*)(Abase + (size_t)(ii * 32 + arow) * 1024 + t * 64 + acol);
    }
  };
  auto awrite = [&](int cb, int i0) {
#pragma unroll
    for (int i = 0; i < 4; ++i) {
      int ii = i0 + i;
      int row = ii * 32 + arow;
      int byte = row * 128 + (((tid & 15) * 8) ^ ((row & 7) << 4));
      half4v h = { (_Float16)areg[ii].x, (_Float16)areg[ii].y,
                   (_Float16)areg[ii].z, (_Float16)areg[ii].w };
      *(half4v*)((char*)&Als[cb][0] + byte) = h;
    }
  };
  auto bissue = [&](int t, int cb) {
    const char* src = (const char*)Bimg + (((size_t)nt * 16 + t) << 15) + wid * 4096 + lane * 16;
    char* dst = (char*)&Bls[cb][0] + wid * 4096;
#pragma unroll
    for (int j = 0; j < 4; ++j)
      gload_lds16(src + j * 1024, dst + j * 1024);
  };
  auto lda = [&](int cb, int mh) {
#pragma unroll
    for (int mf = 0; mf < 4; ++mf)
#pragma unroll
      for (int kk = 0; kk < 2; ++kk) {
        int row = wm * 128 + mh * 64 + mf * 16 + lr;
        int byte = row * 128 + ((kk * 64 + lq * 16) ^ ((row & 7) << 4));
        afr[mf][kk] = *(const half8*)((const char*)&Als[cb][0] + byte);
      }
  };
  auto ldb = [&](int cb, int nh, half8 (&bf)[2][2]) {
#pragma unroll
    for (int j = 0; j < 2; ++j)
#pragma unroll
      for (int kk = 0; kk < 2; ++kk) {
        int row = wn * 64 + (nh * 2 + j) * 16 + lr;
        int byte = row * 128 + ((kk * 64 + lq * 16) ^ ((row & 7) << 4));
        bf[j][kk] = *(const half8*)((const char*)&Bls[cb][0] + byte);
      }
  };
  auto mma = [&](int mh, int nh, half8 (&bf)[2][2]) {
#pragma unroll
    for (int mf = 0; mf < 4; ++mf)
#pragma unroll
      for (int j = 0; j < 2; ++j)
#pragma unroll
        for (int kk = 0; kk < 2; ++kk)
          acc[mh * 4 + mf][nh * 2 + j] = __builtin_amdgcn_mfma_f32_16x16x32_f16(
              afr[mf][kk], bf[j][kk], acc[mh * 4 + mf][nh * 2 + j], 0, 0, 0);
  };

  // ---- prologue: stage K-tile 0 into buf 0 ----
  aissue(0, 0); aissue(0, 4);
  bissue(0, 0);
  awrite(0, 0); awrite(0, 4);   // compiler inserts vmcnt waits for areg use
  asm volatile("s_waitcnt vmcnt(0) lgkmcnt(0)" ::: "memory");
  BAR();

  // ---- main loop: compute buf c (K-tile t), stage t+1 into c^1 ----
  for (int t = 0; t < 16; ++t) {
    const int c = t & 1, c2 = c ^ 1;
    const bool pf = (t < 15);
    // phase 0: A(m-half0) + B(n-half0) frags; issue A loads 0-3 for t+1
    lda(c, 0); ldb(c, 0, bfr0);
    if (pf) aissue(t + 1, 0);
    BAR();
    PRIO1(); mma(0, 0, bfr0); PRIO0();
    BAR();
    // phase 1: B(n-half1) frags; issue A loads 4-7
    ldb(c, 1, bfr1);
    if (pf) aissue(t + 1, 4);
    BAR();
    PRIO1(); mma(0, 1, bfr1); PRIO0();
    BAR();
    // phase 2: A(m-half1) frags; issue B gload_lds; cvt+write A 0-3
    lda(c, 1);
    if (pf) { bissue(t + 1, c2); awrite(c2, 0); }
    BAR();
    PRIO1(); mma(1, 1, bfr1); PRIO0();
    BAR();
    // phase 3: cvt+write A 4-7; last MFMA quadrant; drain before swap
    if (pf) awrite(c2, 4);
    PRIO1(); mma(1, 0, bfr0); PRIO0();
    asm volatile("s_waitcnt vmcnt(0) lgkmcnt(0)" ::: "memory");
    BAR();
  }

  // ---- epilogue: C/D layout col=lr, row=lq*4+r ----
#pragma unroll
  for (int fn = 0; fn < 4; ++fn) {
    int col = col0 + wn * 64 + fn * 16 + lr;
    float bias = (col < 512) ? bias_r[col] : bias_i[col - 512];
#pragma unroll
    for (int fm = 0; fm < 8; ++fm) {
      int r0 = row0 + wm * 128 + fm * 16 + lq * 4;
#pragma unroll
      for (int r = 0; r < 4; ++r)
        C[(size_t)(r0 + r) * 1024 + col] = acc[fm][fn][r] + bias;
    }
  }
}

extern "C" void kernel_launch(void* const* d_in, const int* in_sizes, int n_in,
                              void* d_out, int out_size, void* d_ws, size_t ws_size,
                              hipStream_t stream) {
  const float* x   = (const float*)d_in[0];
  const float* G1R = (const float*)d_in[1];
  const float* G2R = (const float*)d_in[2];
  const float* G1I = (const float*)d_in[3];
  const float* G2I = (const float*)d_in[4];
  const float* br  = (const float*)d_in[5];
  const float* bi  = (const float*)d_in[6];
  float* out = (float*)d_out;
  _Float16* BTimg = (_Float16*)d_ws;  // 2 MB swizzled B tile images

  build_bt<<<4096, 256, 0, stream>>>(G1R, G2R, G1I, G2I, BTimg);
  tt_gemm<<<512, 512, 0, stream>>>(x, BTimg, br, bi, out);
}

// Round 3
// 130.581 us; speedup vs baseline: 1.0483x; 1.0483x over previous
//
#include <hip/hip_runtime.h>
#include <hip/hip_bf16.h>
#include <stdint.h>

// out = X @ Bbig + bias; X = (32768 x 1024) fp32 (real||imag)
//   n<512:  B[k][n] = Wr[n][k] (k<512), -Wi[n][k-512] (k>=512)
//   n>=512: B[k][n] = Wi[n-512][k] (k<512), Wr[n-512][k-512] (k>=512)
// Plan: (1) build swizzled fp16 B tile-image (2 MB), (2) convert X into a
// swizzled fp16 A tile-image (64 MB), (3) m201-style 256x256/BK=64 8-wave
// GEMM where BOTH operands stage via linear global_load_lds from the
// pre-swizzled images. One vmcnt(0)/K-tile on loads issued 2-3 phases prior.

typedef _Float16 half8 __attribute__((ext_vector_type(8)));
typedef _Float16 half4v __attribute__((ext_vector_type(4)));
typedef float f32x4 __attribute__((ext_vector_type(4)));

typedef __attribute__((address_space(3))) void* lds_ptr_t;
typedef const __attribute__((address_space(1))) void* gbl_ptr_t;

__device__ __forceinline__ void gload_lds16(const void* g, void* s) {
  // lane l's 16B from per-lane g land at (wave-uniform) s + l*16
  __builtin_amdgcn_global_load_lds((gbl_ptr_t)g, (lds_ptr_t)s, 16, 0, 0);
}

#define BARF() asm volatile("s_barrier" ::: "memory")
#define VMCNT0() asm volatile("s_waitcnt vmcnt(0)" ::: "memory")
#define PRIO1() __builtin_amdgcn_s_setprio(1)
#define PRIO0() __builtin_amdgcn_s_setprio(0)

// Tile-image byte layout (32 KB per 256-row x 64-col fp16 tile):
//   byte = row*128 + ((kcol*2) ^ ((row&7)<<4))   -- XOR bank swizzle

// ---------------- Kernel 1: swizzled B image (validated in round 2) ----------
__global__ void build_bt(const float* __restrict__ G1R, const float* __restrict__ G2R,
                         const float* __restrict__ G1I, const float* __restrict__ G2I,
                         _Float16* __restrict__ BTimg) {
  int idx = blockIdx.x * 256 + threadIdx.x;  // 0 .. 1M-1
  int kcol = idx & 63;
  int row  = (idx >> 6) & 255;
  int kt   = (idx >> 14) & 15;
  int nt   = idx >> 18;
  int n = nt * 256 + row;
  int k = kt * 64 + kcol;
  int o = n & 511, i = k & 511;
  bool imagOut = n >= 512, kHi = k >= 512;
  const float* G1; const float* G2; float sign = 1.0f;
  if (imagOut == kHi) { G1 = G1R; G2 = G2R; }
  else { G1 = G1I; G2 = G2I; if (!imagOut) sign = -1.0f; }
  int b = o >> 4, e = o & 15, d = i >> 4, g = i & 15;
  float w = 0.0f;
#pragma unroll
  for (int c = 0; c < 4; ++c)
    w += G1[b * 128 + c * 32 + d] * G2[c * 256 + e * 16 + g];
  size_t byteoff = ((size_t)(nt * 16 + kt) << 15) + (size_t)row * 128
                 + ((kcol * 2) ^ ((row & 7) << 4));
  *(_Float16*)((char*)BTimg + byteoff) = (_Float16)(sign * w);
}

// ---------------- Kernel 2: X fp32 -> swizzled fp16 A image ----------------
// Aimg tile (mt,kt) holds rows mt*256..+255, k kt*64..+63.
__global__ __launch_bounds__(256) void build_at(const float* __restrict__ A,
                                                _Float16* __restrict__ Aimg) {
  const int tid = threadIdx.x;
  const int kt = blockIdx.x & 15, mt = blockIdx.x >> 4;
  const float* src = A + (size_t)mt * 256 * 1024 + kt * 64;
  char* dst = (char*)Aimg + ((size_t)(mt * 16 + kt) << 15);
  const int cg = tid & 15;        // col group (4 floats)
  const int rb = tid >> 4;        // row base
#pragma unroll
  for (int r = 0; r < 16; ++r) {
    int row = rb + r * 16;        // 0..255
    float4 v = *(const float4*)(src + (size_t)row * 1024 + cg * 4);
    half4v h = { (_Float16)v.x, (_Float16)v.y, (_Float16)v.z, (_Float16)v.w };
    *(half4v*)(dst + row * 128 + ((cg * 8) ^ ((row & 7) << 4))) = h;
  }
}

// ---------------- Kernel 3: GEMM, m201-style schedule ----------------
__global__ __launch_bounds__(512, 2) void tt_gemm(
    const _Float16* __restrict__ Aimg, const _Float16* __restrict__ Bimg,
    const float* __restrict__ bias_r, const float* __restrict__ bias_i,
    float* __restrict__ C) {
  __shared__ __align__(16) _Float16 Als[2][16384];  // 32KB/buf, 256 rows x 64k swz
  __shared__ __align__(16) _Float16 Bls[2][16384];

  const int tid = threadIdx.x;
  const int bid = blockIdx.x;
  // XCD swizzle (512 % 8 == 0): 64 contiguous per XCD, nt fastest (A L2 reuse)
  const int bid2 = (bid & 7) * 64 + (bid >> 3);
  const int mt = bid2 >> 2, nt = bid2 & 3;

  const int lane = tid & 63, wid = tid >> 6;
  const int wm = wid >> 2, wn = wid & 3;   // wave -> 128(M) x 64(N) C subtile
  const int lr = lane & 15, lq = lane >> 4;

  f32x4 acc[8][4] = {};
  half8 afr0[4][2], afr1[4][2], bfr0[2][2], bfr1[2][2];

  const char* Abase = (const char*)Aimg + ((size_t)mt << 19);  // mt*16 tiles * 32KB
  const char* Bbase = (const char*)Bimg + ((size_t)nt << 19);
  const int soff = wid * 1024 + lane * 16;
  const int doff = wid * 1024;

  auto stage = [&](const char* base, int t, _Float16* ldsbuf) {
    const char* s = base + ((size_t)t << 15) + soff;
    char* d = (char*)ldsbuf + doff;
#pragma unroll
    for (int j = 0; j < 4; ++j)
      gload_lds16(s + j * 8192, d + j * 8192);
  };
  auto lda = [&](const _Float16* buf, int mh, half8 (&af)[4][2]) {
#pragma unroll
    for (int mf = 0; mf < 4; ++mf)
#pragma unroll
      for (int kk = 0; kk < 2; ++kk) {
        int row = wm * 128 + mh * 64 + mf * 16 + lr;
        int byte = row * 128 + ((kk * 64 + lq * 16) ^ ((row & 7) << 4));
        af[mf][kk] = *(const half8*)((const char*)buf + byte);
      }
  };
  auto ldb = [&](const _Float16* buf, int nh, half8 (&bf)[2][2]) {
#pragma unroll
    for (int j = 0; j < 2; ++j)
#pragma unroll
      for (int kk = 0; kk < 2; ++kk) {
        int row = wn * 64 + (nh * 2 + j) * 16 + lr;
        int byte = row * 128 + ((kk * 64 + lq * 16) ^ ((row & 7) << 4));
        bf[j][kk] = *(const half8*)((const char*)buf + byte);
      }
  };
  auto mmaq = [&](half8 (&af)[4][2], half8 (&bf)[2][2], int mb, int nb) {
#pragma unroll
    for (int mf = 0; mf < 4; ++mf)
#pragma unroll
      for (int j = 0; j < 2; ++j)
#pragma unroll
        for (int kk = 0; kk < 2; ++kk)
          acc[mb + mf][nb + j] = __builtin_amdgcn_mfma_f32_16x16x32_f16(
              af[mf][kk], bf[j][kk], acc[mb + mf][nb + j], 0, 0, 0);
  };

  // ---- prologue: stage K-tile 0 ----
  stage(Abase, 0, Als[0]);
  stage(Bbase, 0, Bls[0]);
  VMCNT0();
  BARF();

  for (int t = 0; t < 16; ++t) {
    const int c = t & 1;
    _Float16* Ac = Als[c];  _Float16* Bc = Bls[c];
    _Float16* An = Als[c ^ 1]; _Float16* Bn = Bls[c ^ 1];
    const bool pf = (t < 15);
    // P0: frags (A mh0: 8 ds, B nh0: 4 ds); issue A stage for t+1
    lda(Ac, 0, afr0); ldb(Bc, 0, bfr0);
    if (pf) stage(Abase, t + 1, An);
    BARF(); PRIO1(); mmaq(afr0, bfr0, 0, 0); PRIO0(); BARF();
    // P1: frags (B nh1: 4 ds); issue B stage for t+1
    ldb(Bc, 1, bfr1);
    if (pf) stage(Bbase, t + 1, Bn);
    BARF(); PRIO1(); mmaq(afr0, bfr1, 0, 2); PRIO0(); BARF();
    // P2: frags (A mh1: 8 ds)
    lda(Ac, 1, afr1);
    BARF(); PRIO1(); mmaq(afr1, bfr1, 4, 2); PRIO0(); BARF();
    // P3: wait t+1 stages (issued 2-3 phases ago -> ~free), last quadrant
    VMCNT0();
    BARF(); PRIO1(); mmaq(afr1, bfr0, 4, 0); PRIO0(); BARF();
  }

  // ---- epilogue: C/D layout col=lr, row=lq*4+r ----
  const int row0 = mt * 256, col0 = nt * 256;
#pragma unroll
  for (int fn = 0; fn < 4; ++fn) {
    int col = col0 + wn * 64 + fn * 16 + lr;
    float bias = (col < 512) ? bias_r[col] : bias_i[col - 512];
#pragma unroll
    for (int fm = 0; fm < 8; ++fm) {
      // acc row-frag index fm -> row offset (fm>>2)*64 + (fm&3)*16
      int r0 = row0 + wm * 128 + (fm >> 2) * 64 + (fm & 3) * 16 + lq * 4;
#pragma unroll
      for (int r = 0; r < 4; ++r)
        C[(size_t)(r0 + r) * 1024 + col] = acc[fm][fn][r] + bias;
    }
  }
}

// ---------------- Fallback (round-1, known-good, 2 MB ws) ----------------
__global__ void build_bt_flat(const float* __restrict__ G1R, const float* __restrict__ G2R,
                              const float* __restrict__ G1I, const float* __restrict__ G2I,
                              _Float16* __restrict__ BT) {
  int idx = blockIdx.x * 256 + threadIdx.x;
  int n = idx >> 10, k = idx & 1023;
  int o = n & 511, i = k & 511;
  bool imagOut = n >= 512, kHi = k >= 512;
  const float* G1; const float* G2; float sign = 1.0f;
  if (imagOut == kHi) { G1 = G1R; G2 = G2R; }
  else { G1 = G1I; G2 = G2I; if (!imagOut) sign = -1.0f; }
  int b = o >> 4, e = o & 15, d = i >> 4, g = i & 15;
  float w = 0.0f;
#pragma unroll
  for (int c = 0; c < 4; ++c)
    w += G1[b * 128 + c * 32 + d] * G2[c * 256 + e * 16 + g];
  BT[idx] = (_Float16)(sign * w);
}

__global__ __launch_bounds__(256, 2) void tt_gemm_fb(
    const float* __restrict__ A, const _Float16* __restrict__ BT,
    const float* __restrict__ bias_r, const float* __restrict__ bias_i,
    float* __restrict__ C) {
  __shared__ __align__(16) _Float16 Als[128 * 32];
  __shared__ __align__(16) _Float16 Bls[128 * 32];
  const int tid = threadIdx.x;
  const int bid = blockIdx.x;
  const int bid2 = (bid & 7) * 256 + (bid >> 3);
  const int mt = bid2 >> 3, nt = bid2 & 7;
  const int row0 = mt * 128, col0 = nt * 128;
  const int lane = tid & 63, wid = tid >> 6;
  const int wm = wid >> 1, wn = wid & 1;
  const int lr = lane & 15, lq = lane >> 4;
  f32x4 acc[4][4] = {};
  const int brow_base = wid * 32 + (lane >> 2);
  const int bk = (lane & 3) * 8;
  const float* Abase = A + (size_t)row0 * 1024;
  for (int kt = 0; kt < 32; ++kt) {
    const int k0 = kt * 32;
    float4 va[4];
#pragma unroll
    for (int i = 0; i < 4; ++i) {
      int fid = i * 256 + tid;
      int ar = fid >> 3, aq = fid & 7;
      va[i] = *(const float4*)(Abase + (size_t)ar * 1024 + k0 + aq * 4);
    }
    __syncthreads();
#pragma unroll
    for (int i = 0; i < 4; ++i) {
      int fid = i * 256 + tid;
      int ar = fid >> 3, aq = fid & 7;
      half4v h = { (_Float16)va[i].x, (_Float16)va[i].y,
                   (_Float16)va[i].z, (_Float16)va[i].w };
      *(half4v*)&Als[ar * 32 + aq * 4] = h;
    }
#pragma unroll
    for (int j = 0; j < 2; ++j)
      gload_lds16(BT + (size_t)(col0 + brow_base + j * 16) * 1024 + k0 + bk,
                  (char*)Bls + (wid * 2 + j) * 1024);
    __syncthreads();
    half8 af[4], bf[4];
#pragma unroll
    for (int m = 0; m < 4; ++m)
      af[m] = *(const half8*)&Als[(wm * 64 + m * 16 + lr) * 32 + lq * 8];
#pragma unroll
    for (int n = 0; n < 4; ++n)
      bf[n] = *(const half8*)&Bls[(wn * 64 + n * 16 + lr) * 32 + lq * 8];
#pragma unroll
    for (int m = 0; m < 4; ++m)
#pragma unroll
      for (int n = 0; n < 4; ++n)
        acc[m][n] = __builtin_amdgcn_mfma_f32_16x16x32_f16(af[m], bf[n], acc[m][n], 0, 0, 0);
  }
#pragma unroll
  for (int n = 0; n < 4; ++n) {
    int col = col0 + wn * 64 + n * 16 + lr;
    float bias = (col < 512) ? bias_r[col] : bias_i[col - 512];
#pragma unroll
    for (int m = 0; m < 4; ++m) {
      int r0 = row0 + wm * 64 + m * 16 + lq * 4;
#pragma unroll
      for (int r = 0; r < 4; ++r)
        C[(size_t)(r0 + r) * 1024 + col] = acc[m][n][r] + bias;
    }
  }
}

extern "C" void kernel_launch(void* const* d_in, const int* in_sizes, int n_in,
                              void* d_out, int out_size, void* d_ws, size_t ws_size,
                              hipStream_t stream) {
  const float* x   = (const float*)d_in[0];
  const float* G1R = (const float*)d_in[1];
  const float* G2R = (const float*)d_in[2];
  const float* G1I = (const float*)d_in[3];
  const float* G2I = (const float*)d_in[4];
  const float* br  = (const float*)d_in[5];
  const float* bi  = (const float*)d_in[6];
  float* out = (float*)d_out;

  const size_t BIMG_BYTES = 2u << 20;            // 2 MB
  const size_t AIMG_BYTES = (size_t)64 << 20;    // 64 MB
  if (ws_size >= BIMG_BYTES + AIMG_BYTES) {
    _Float16* Bimg = (_Float16*)d_ws;
    _Float16* Aimg = (_Float16*)((char*)d_ws + BIMG_BYTES);
    build_bt<<<4096, 256, 0, stream>>>(G1R, G2R, G1I, G2I, Bimg);
    build_at<<<2048, 256, 0, stream>>>(x, Aimg);
    tt_gemm<<<512, 512, 0, stream>>>(Aimg, Bimg, br, bi, out);
  } else {
    _Float16* BT = (_Float16*)d_ws;  // 2 MB flat
    build_bt_flat<<<4096, 256, 0, stream>>>(G1R, G2R, G1I, G2I, BT);
    tt_gemm_fb<<<2048, 256, 0, stream>>>(x, BT, br, bi, out);
  }
}

// Round 4
// 121.193 us; speedup vs baseline: 1.1295x; 1.0775x over previous
//
#include <hip/hip_runtime.h>
#include <hip/hip_bf16.h>
#include <stdint.h>

// out = X @ Bbig + bias; X = (32768 x 1024) fp32 (real||imag)
//   n<512:  B[k][n] = Wr[n][k] (k<512), -Wi[n][k-512] (k>=512)
//   n>=512: B[k][n] = Wi[n-512][k] (k<512), Wr[n-512][k-512] (k>=512)
// Fused plan: (1) build swizzled fp16 B tile-image (2 MB, validated r2/r3);
// (2) single GEMM 256x256/BK=64, 8 waves, 4-phase K-loop:
//     - A: fp32 x loaded direct (8 float4/thr, issued 1 K-tile early),
//       cvt->fp16 + XOR-swizzled ds_write at P3 (T14 issue-early/write-late)
//     - B: linear global_load_lds from pre-swizzled image, issued 2 K-tiles
//       early (P2 of t stages t+2)
//     - ONE counted wait per K-tile: s_waitcnt vmcnt(4) (B(t+2) stays in
//       flight across the boundary). No vmcnt(0) in steady state (T4).

typedef _Float16 half8 __attribute__((ext_vector_type(8)));
typedef _Float16 half4v __attribute__((ext_vector_type(4)));
typedef float f32x4 __attribute__((ext_vector_type(4)));

typedef __attribute__((address_space(3))) void* lds_ptr_t;
typedef const __attribute__((address_space(1))) void* gbl_ptr_t;

__device__ __forceinline__ void gload_lds16(const void* g, void* s) {
  // lane l's 16B from per-lane g land at (wave-uniform) s + l*16
  __builtin_amdgcn_global_load_lds((gbl_ptr_t)g, (lds_ptr_t)s, 16, 0, 0);
}

#define BARF() asm volatile("s_barrier" ::: "memory")
#define PRIO1() __builtin_amdgcn_s_setprio(1)
#define PRIO0() __builtin_amdgcn_s_setprio(0)

// Tile byte layout (32 KB per 256-row x 64-col fp16 tile):
//   byte = row*128 + ((kcol*2) ^ ((row&7)<<4))   -- XOR bank swizzle

// ---------------- Kernel 1: swizzled B image (validated) ----------------
__global__ void build_bt(const float* __restrict__ G1R, const float* __restrict__ G2R,
                         const float* __restrict__ G1I, const float* __restrict__ G2I,
                         _Float16* __restrict__ BTimg) {
  int idx = blockIdx.x * 256 + threadIdx.x;  // 0 .. 1M-1
  int kcol = idx & 63;
  int row  = (idx >> 6) & 255;
  int kt   = (idx >> 14) & 15;
  int nt   = idx >> 18;
  int n = nt * 256 + row;
  int k = kt * 64 + kcol;
  int o = n & 511, i = k & 511;
  bool imagOut = n >= 512, kHi = k >= 512;
  const float* G1; const float* G2; float sign = 1.0f;
  if (imagOut == kHi) { G1 = G1R; G2 = G2R; }
  else { G1 = G1I; G2 = G2I; if (!imagOut) sign = -1.0f; }
  int b = o >> 4, e = o & 15, d = i >> 4, g = i & 15;
  float w = 0.0f;
#pragma unroll
  for (int c = 0; c < 4; ++c)
    w += G1[b * 128 + c * 32 + d] * G2[c * 256 + e * 16 + g];
  size_t byteoff = ((size_t)(nt * 16 + kt) << 15) + (size_t)row * 128
                 + ((kcol * 2) ^ ((row & 7) << 4));
  *(_Float16*)((char*)BTimg + byteoff) = (_Float16)(sign * w);
}

// ---------------- Kernel 2: fused GEMM ----------------
__global__ __launch_bounds__(512, 2) void tt_gemm(
    const float* __restrict__ A,       // 32768 x 1024 fp32 (x)
    const _Float16* __restrict__ Bimg, // swizzled tile images, 2 MB
    const float* __restrict__ bias_r, const float* __restrict__ bias_i,
    float* __restrict__ C) {
  __shared__ __align__(16) _Float16 Als[2][16384];  // 32KB/buf, swizzled
  __shared__ __align__(16) _Float16 Bls[2][16384];

  const int tid = threadIdx.x;
  const int bid = blockIdx.x;
  // XCD swizzle (512 % 8 == 0): 64 contiguous per XCD, nt fastest (A L2 reuse)
  const int bid2 = (bid & 7) * 64 + (bid >> 3);
  const int mt = bid2 >> 2, nt = bid2 & 3;

  const int lane = tid & 63, wid = tid >> 6;
  const int wm = wid >> 2, wn = wid & 3;   // wave -> 128(M) x 64(N) C subtile
  const int lr = lane & 15, lq = lane >> 4;

  f32x4 acc[8][4] = {};
  float4 areg[8];
  half8 afr0[4][2], afr1[4][2], bfr0[2][2], bfr1[2][2];

  const float* Abase = A + (size_t)mt * 256 * 1024;
  const char* Bbase = (const char*)Bimg + ((size_t)nt << 19);
  const int arow = tid >> 4;          // 0..31
  const int acg  = tid & 15;          // col group of 4 floats
  const int awxor = (arow & 7) << 4;  // write-side XOR (row&7 == arow&7)
  const int soff = wid * 1024 + lane * 16;
  const int doff = wid * 1024;

  auto aload = [&](int t) {           // 8 x global_load_dwordx4
#pragma unroll
    for (int ii = 0; ii < 8; ++ii)
      areg[ii] = *(const float4*)(Abase + (size_t)(ii * 32 + arow) * 1024 + t * 64 + acg * 4);
  };
  auto awrite = [&](_Float16* buf) {  // cvt + 8 x ds_write_b64 (swizzled)
#pragma unroll
    for (int ii = 0; ii < 8; ++ii) {
      int row = ii * 32 + arow;
      half4v h = { (_Float16)areg[ii].x, (_Float16)areg[ii].y,
                   (_Float16)areg[ii].z, (_Float16)areg[ii].w };
      *(half4v*)((char*)buf + row * 128 + ((acg * 8) ^ awxor)) = h;
    }
  };
  auto bissue = [&](int t, _Float16* ldsbuf) {  // 4 x gload_lds16 per wave
    const char* s = Bbase + ((size_t)t << 15) + soff;
    char* d = (char*)ldsbuf + doff;
#pragma unroll
    for (int j = 0; j < 4; ++j)
      gload_lds16(s + j * 8192, d + j * 8192);
  };
  auto lda = [&](const _Float16* buf, int mh, half8 (&af)[4][2]) {
#pragma unroll
    for (int mf = 0; mf < 4; ++mf)
#pragma unroll
      for (int kk = 0; kk < 2; ++kk) {
        int row = wm * 128 + mh * 64 + mf * 16 + lr;
        int byte = row * 128 + ((kk * 64 + lq * 16) ^ ((row & 7) << 4));
        af[mf][kk] = *(const half8*)((const char*)buf + byte);
      }
  };
  auto ldb = [&](const _Float16* buf, int nh, half8 (&bf)[2][2]) {
#pragma unroll
    for (int j = 0; j < 2; ++j)
#pragma unroll
      for (int kk = 0; kk < 2; ++kk) {
        int row = wn * 64 + (nh * 2 + j) * 16 + lr;
        int byte = row * 128 + ((kk * 64 + lq * 16) ^ ((row & 7) << 4));
        bf[j][kk] = *(const half8*)((const char*)buf + byte);
      }
  };
  auto mmaq = [&](half8 (&af)[4][2], half8 (&bf)[2][2], int mb, int nb) {
#pragma unroll
    for (int mf = 0; mf < 4; ++mf)
#pragma unroll
      for (int j = 0; j < 2; ++j)
#pragma unroll
        for (int kk = 0; kk < 2; ++kk)
          acc[mb + mf][nb + j] = __builtin_amdgcn_mfma_f32_16x16x32_f16(
              af[mf][kk], bf[j][kk], acc[mb + mf][nb + j], 0, 0, 0);
  };

  // ---- prologue: A(0)->regs (oldest), B(0), B(1) in flight ----
  aload(0);                 // 8 vmem
  bissue(0, Bls[0]);        // 4 vmem
  bissue(1, Bls[1]);        // 4 vmem (stays in flight)
  asm volatile("s_waitcnt vmcnt(4)" ::: "memory");  // A(0)+B(0) done
  awrite(Als[0]);
  asm volatile("s_waitcnt lgkmcnt(0)" ::: "memory");
  BARF();

  // ---- main loop: compute tile t from buf c; steady-state prefetch:
  //      A(t+1) regs at P0, B(t+2) gload at P2, single vmcnt(4) at P3 ----
  for (int t = 0; t < 16; ++t) {
    const int c = t & 1, nc = c ^ 1;
    _Float16* Ac = Als[c];  _Float16* Bc = Bls[c];
    // P0
    lda(Ac, 0, afr0); ldb(Bc, 0, bfr0);
    if (t < 15) aload(t + 1);
    BARF(); PRIO1(); mmaq(afr0, bfr0, 0, 0); PRIO0(); BARF();
    // P1
    ldb(Bc, 1, bfr1);
    BARF(); PRIO1(); mmaq(afr0, bfr1, 0, 2); PRIO0(); BARF();
    // P2
    lda(Ac, 1, afr1);
    if (t < 14) bissue(t + 2, Bls[c]);   // Bls[c] reads finished at P1
    BARF(); PRIO1(); mmaq(afr1, bfr1, 4, 2); PRIO0(); BARF();
    // P3 (no pre-barrier: operands already in regs)
    PRIO1(); mmaq(afr1, bfr0, 4, 0); PRIO0();
    if (t < 15) {
      if (t < 14) {
        // outstanding: A(t+1)x8 (old) + B(t+2)x4 (new) -> complete A+B(t+1)
        asm volatile("s_waitcnt vmcnt(4)" ::: "memory");
      } else {
        asm volatile("s_waitcnt vmcnt(0)" ::: "memory");
      }
      awrite(Als[nc]);
      asm volatile("s_waitcnt lgkmcnt(0)" ::: "memory");
    }
    BARF();
  }

  // ---- epilogue: C/D layout col=lr, row=lq*4+r ----
  const int row0 = mt * 256, col0 = nt * 256;
#pragma unroll
  for (int fn = 0; fn < 4; ++fn) {
    int col = col0 + wn * 64 + fn * 16 + lr;
    float bias = (col < 512) ? bias_r[col] : bias_i[col - 512];
#pragma unroll
    for (int fm = 0; fm < 8; ++fm) {
      int r0 = row0 + wm * 128 + (fm >> 2) * 64 + (fm & 3) * 16 + lq * 4;
#pragma unroll
      for (int r = 0; r < 4; ++r)
        C[(size_t)(r0 + r) * 1024 + col] = acc[fm][fn][r] + bias;
    }
  }
}

extern "C" void kernel_launch(void* const* d_in, const int* in_sizes, int n_in,
                              void* d_out, int out_size, void* d_ws, size_t ws_size,
                              hipStream_t stream) {
  const float* x   = (const float*)d_in[0];
  const float* G1R = (const float*)d_in[1];
  const float* G2R = (const float*)d_in[2];
  const float* G1I = (const float*)d_in[3];
  const float* G2I = (const float*)d_in[4];
  const float* br  = (const float*)d_in[5];
  const float* bi  = (const float*)d_in[6];
  float* out = (float*)d_out;
  _Float16* Bimg = (_Float16*)d_ws;  // 2 MB swizzled B tile images

  build_bt<<<4096, 256, 0, stream>>>(G1R, G2R, G1I, G2I, Bimg);
  tt_gemm<<<512, 512, 0, stream>>>(x, Bimg, br, bi, out);
}

// Round 5
// 116.570 us; speedup vs baseline: 1.1743x; 1.0397x over previous
//
#include <hip/hip_runtime.h>
#include <hip/hip_bf16.h>
#include <stdint.h>

// out = X @ Bbig + bias; X = (32768 x 1024) fp32 (real||imag)
//   n<512:  B[k][n] = Wr[n][k] (k<512), -Wi[n][k-512] (k>=512)
//   n>=512: B[k][n] = Wi[n-512][k] (k<512), Wr[n-512][k-512] (k>=512)
// Fused single-GEMM plan (256x256 tile, BK=64, 8 waves 2Mx4N, fp16 MFMA):
//   - B: linear global_load_lds from pre-swizzled 2MB image (L2-resident),
//     issued at P0 for t+1 (3-phase cover).
//   - A: fp32 x -> regs (aload, issued at P2 for t+2 -> consumed at P1 of
//     t+1 by cvt+swizzled ds_write). A x-loads NEVER drained at a barrier:
//     per-tile wait is vmcnt(8) (B only); A completion is the compiler's
//     mid-phase vmcnt(4) before awrite.
//   - One barrier rhythm: 4 phases x {frag ds_reads | stage | BAR | MFMA | BAR}.

typedef _Float16 half8 __attribute__((ext_vector_type(8)));
typedef _Float16 half4v __attribute__((ext_vector_type(4)));
typedef float f32x4 __attribute__((ext_vector_type(4)));

typedef __attribute__((address_space(3))) void* lds_ptr_t;
typedef const __attribute__((address_space(1))) void* gbl_ptr_t;

__device__ __forceinline__ void gload_lds16(const void* g, void* s) {
  // lane l's 16B from per-lane g land at (wave-uniform) s + l*16
  __builtin_amdgcn_global_load_lds((gbl_ptr_t)g, (lds_ptr_t)s, 16, 0, 0);
}

#define BARF() asm volatile("s_barrier" ::: "memory")
#define PRIO1() __builtin_amdgcn_s_setprio(1)
#define PRIO0() __builtin_amdgcn_s_setprio(0)

// Tile byte layout (32 KB per 256-row x 64-col fp16 tile):
//   byte = row*128 + ((kcol*2) ^ ((row&7)<<4))   -- XOR bank swizzle

// ---------------- Kernel 1: swizzled B image (validated r2-r4) ----------------
__global__ void build_bt(const float* __restrict__ G1R, const float* __restrict__ G2R,
                         const float* __restrict__ G1I, const float* __restrict__ G2I,
                         _Float16* __restrict__ BTimg) {
  int idx = blockIdx.x * 256 + threadIdx.x;  // 0 .. 1M-1
  int kcol = idx & 63;
  int row  = (idx >> 6) & 255;
  int kt   = (idx >> 14) & 15;
  int nt   = idx >> 18;
  int n = nt * 256 + row;
  int k = kt * 64 + kcol;
  int o = n & 511, i = k & 511;
  bool imagOut = n >= 512, kHi = k >= 512;
  const float* G1; const float* G2; float sign = 1.0f;
  if (imagOut == kHi) { G1 = G1R; G2 = G2R; }
  else { G1 = G1I; G2 = G2I; if (!imagOut) sign = -1.0f; }
  int b = o >> 4, e = o & 15, d = i >> 4, g = i & 15;
  float w = 0.0f;
#pragma unroll
  for (int c = 0; c < 4; ++c)
    w += G1[b * 128 + c * 32 + d] * G2[c * 256 + e * 16 + g];
  size_t byteoff = ((size_t)(nt * 16 + kt) << 15) + (size_t)row * 128
                 + ((kcol * 2) ^ ((row & 7) << 4));
  *(_Float16*)((char*)BTimg + byteoff) = (_Float16)(sign * w);
}

// ---------------- Kernel 2: fused GEMM ----------------
__global__ __launch_bounds__(512, 2) void tt_gemm(
    const float* __restrict__ A,       // 32768 x 1024 fp32 (x)
    const _Float16* __restrict__ Bimg, // swizzled tile images, 2 MB
    const float* __restrict__ bias_r, const float* __restrict__ bias_i,
    float* __restrict__ C) {
  __shared__ __align__(16) _Float16 Als[2][16384];  // 32KB/buf, swizzled
  __shared__ __align__(16) _Float16 Bls[2][16384];

  const int tid = threadIdx.x;
  const int bid = blockIdx.x;
  // XCD swizzle (512 % 8 == 0): 64 contiguous per XCD, nt fastest (A L2 reuse)
  const int bid2 = (bid & 7) * 64 + (bid >> 3);
  const int mt = bid2 >> 2, nt = bid2 & 3;

  const int lane = tid & 63, wid = tid >> 6;
  const int wm = wid >> 2, wn = wid & 3;   // wave -> 128(M) x 64(N) C subtile
  const int lr = lane & 15, lq = lane >> 4;

  f32x4 acc[8][4] = {};
  float4 areg[8];
  half8 afr0[4][2], afr1[4][2], bfr0[2][2], bfr1[2][2];

  const float* Abase = A + (size_t)mt * 256 * 1024;
  const char* Bbase = (const char*)Bimg + ((size_t)nt << 19);
  const int arow = tid >> 4;          // 0..31
  const int acg  = tid & 15;          // col group of 4 floats
  const int awxor = (arow & 7) << 4;  // write-side XOR (row&7 == arow&7)
  const int soff = wid * 1024 + lane * 16;
  const int doff = wid * 1024;

  auto aload = [&](int t) {           // 8 x global_load_dwordx4 (x for tile t)
#pragma unroll
    for (int ii = 0; ii < 8; ++ii)
      areg[ii] = *(const float4*)(Abase + (size_t)(ii * 32 + arow) * 1024 + t * 64 + acg * 4);
  };
  auto awrite = [&](_Float16* buf) {  // cvt + 8 x ds_write_b64 (swizzled)
#pragma unroll
    for (int ii = 0; ii < 8; ++ii) {
      int row = ii * 32 + arow;
      half4v h = { (_Float16)areg[ii].x, (_Float16)areg[ii].y,
                   (_Float16)areg[ii].z, (_Float16)areg[ii].w };
      *(half4v*)((char*)buf + row * 128 + ((acg * 8) ^ awxor)) = h;
    }
  };
  auto bissue = [&](int t, _Float16* ldsbuf) {  // 4 x gload_lds16 per wave
    const char* s = Bbase + ((size_t)t << 15) + soff;
    char* d = (char*)ldsbuf + doff;
#pragma unroll
    for (int j = 0; j < 4; ++j)
      gload_lds16(s + j * 8192, d + j * 8192);
  };
  auto lda = [&](const _Float16* buf, int mh, half8 (&af)[4][2]) {
#pragma unroll
    for (int mf = 0; mf < 4; ++mf)
#pragma unroll
      for (int kk = 0; kk < 2; ++kk) {
        int row = wm * 128 + mh * 64 + mf * 16 + lr;
        int byte = row * 128 + ((kk * 64 + lq * 16) ^ ((row & 7) << 4));
        af[mf][kk] = *(const half8*)((const char*)buf + byte);
      }
  };
  auto ldb = [&](const _Float16* buf, int nh, half8 (&bf)[2][2]) {
#pragma unroll
    for (int j = 0; j < 2; ++j)
#pragma unroll
      for (int kk = 0; kk < 2; ++kk) {
        int row = wn * 64 + (nh * 2 + j) * 16 + lr;
        int byte = row * 128 + ((kk * 64 + lq * 16) ^ ((row & 7) << 4));
        bf[j][kk] = *(const half8*)((const char*)buf + byte);
      }
  };
  auto mmaq = [&](half8 (&af)[4][2], half8 (&bf)[2][2], int mb, int nb) {
#pragma unroll
    for (int mf = 0; mf < 4; ++mf)
#pragma unroll
      for (int j = 0; j < 2; ++j)
#pragma unroll
        for (int kk = 0; kk < 2; ++kk)
          acc[mb + mf][nb + j] = __builtin_amdgcn_mfma_f32_16x16x32_f16(
              af[mf][kk], bf[j][kk], acc[mb + mf][nb + j], 0, 0, 0);
  };

  // ---- prologue ----
  aload(0);                 // 8 vmem (oldest)
  bissue(0, Bls[0]);        // 4 vmem
  awrite(Als[0]);           // compiler inserts vmcnt(4): A(0) done, B(0) flies
  aload(1);                 // 8 vmem -> areg now holds x(1)
  asm volatile("s_waitcnt vmcnt(8)" ::: "memory");   // B(0) landed
  asm volatile("s_waitcnt lgkmcnt(0)" ::: "memory"); // A(0) ds_writes done
  BARF();

  // ---- main loop over 16 K-tiles ----
  for (int t = 0; t < 16; ++t) {
    const int c = t & 1;
    _Float16* Ac = Als[c];  _Float16* Bc = Bls[c];
    _Float16* An = Als[c ^ 1]; _Float16* Bn = Bls[c ^ 1];
    // P0: frags A(mh0) 8ds + B(nh0) 4ds; issue B stage t+1 (L2-fast)
    lda(Ac, 0, afr0); ldb(Bc, 0, bfr0);
    if (t < 15) bissue(t + 1, Bn);
    BARF(); PRIO1(); mmaq(afr0, bfr0, 0, 0); PRIO0(); BARF();
    // P1: frags B(nh1) 4ds; cvt+write A(t+1) from areg (loaded P2 of t-1)
    ldb(Bc, 1, bfr1);
    if (t < 15) awrite(An);
    BARF(); PRIO1(); mmaq(afr0, bfr1, 0, 2); PRIO0(); BARF();
    // P2: frags A(mh1) 8ds; issue x loads for t+2 (deep, never drained)
    lda(Ac, 1, afr1);
    if (t < 14) aload(t + 2);
    BARF(); PRIO1(); mmaq(afr1, bfr1, 4, 2); PRIO0(); BARF();
    // P3: reg-only MFMA; counted wait: B(t+1) done, A(t+2) stays in flight
    PRIO1(); mmaq(afr1, bfr0, 4, 0); PRIO0();
    if (t < 14) {
      asm volatile("s_waitcnt vmcnt(8)" ::: "memory");   // B(t+1)x4 done
      asm volatile("s_waitcnt lgkmcnt(0)" ::: "memory"); // A ds_writes done
      BARF();
    } else if (t == 14) {
      asm volatile("s_waitcnt vmcnt(0)" ::: "memory");   // B(15) done
      asm volatile("s_waitcnt lgkmcnt(0)" ::: "memory");
      BARF();
    }
  }

  // ---- epilogue: C/D layout col=lr, row=lq*4+r ----
  const int row0 = mt * 256, col0 = nt * 256;
#pragma unroll
  for (int fn = 0; fn < 4; ++fn) {
    int col = col0 + wn * 64 + fn * 16 + lr;
    float bias = (col < 512) ? bias_r[col] : bias_i[col - 512];
#pragma unroll
    for (int fm = 0; fm < 8; ++fm) {
      int r0 = row0 + wm * 128 + (fm >> 2) * 64 + (fm & 3) * 16 + lq * 4;
#pragma unroll
      for (int r = 0; r < 4; ++r)
        C[(size_t)(r0 + r) * 1024 + col] = acc[fm][fn][r] + bias;
    }
  }
}

extern "C" void kernel_launch(void* const* d_in, const int* in_sizes, int n_in,
                              void* d_out, int out_size, void* d_ws, size_t ws_size,
                              hipStream_t stream) {
  const float* x   = (const float*)d_in[0];
  const float* G1R = (const float*)d_in[1];
  const float* G2R = (const float*)d_in[2];
  const float* G1I = (const float*)d_in[3];
  const float* G2I = (const float*)d_in[4];
  const float* br  = (const float*)d_in[5];
  const float* bi  = (const float*)d_in[6];
  float* out = (float*)d_out;
  _Float16* Bimg = (_Float16*)d_ws;  // 2 MB swizzled B tile images

  build_bt<<<4096, 256, 0, stream>>>(G1R, G2R, G1I, G2I, Bimg);
  tt_gemm<<<512, 512, 0, stream>>>(x, Bimg, br, bi, out);
}